// Round 5
// baseline (405.353 us; speedup 1.0000x reference)
//
#include <hip/hip_runtime.h>

#define SIDE 9
#define STATE 81
#define NA 5
#define NJ (STATE * NA)   // 405
#define H1 32
#define H2 32

#define CCH 27            // chunk columns (405 = 15*27, 81 = 3*27)
#define BROWS 256         // rows per 256-thread block (4 waves)
#define NAF 15            // af chunks
#define NCH 18            // 15 af + 3 demand
#define OBS_STRIDE (3 * STATE)

// Compile-time inflow destination table: j = s*NA + a  ->  dest state.
struct DstTab { int v[NJ]; };
constexpr DstTab make_dst() {
    DstTab t{};
    const int dr[NA] = {0, -1, 1, 0, 0};
    const int dc[NA] = {0, 0, 0, -1, 1};
    for (int s = 0; s < STATE; ++s) {
        int r = s / SIDE, c = s % SIDE;
        for (int a = 0; a < NA; ++a) {
            int nr = r + dr[a], nc = c + dc[a];
            int d = (nr >= 0 && nr < SIDE && nc >= 0 && nc < SIDE) ? nr * SIDE + nc : s;
            t.v[s * NA + a] = d;
        }
    }
    return t;
}
constexpr DstTab DST = make_dst();

// waves_per_eu(2,2): pin allocator to 2 waves/EU (VGPR cap 256). Live set is
// nsc[81]+stgA[27]+stgB[27]+offs[27] ~ 175 VGPRs; default heuristic spilled
// (R3: VGPR=84, scratch RMW dominated). Grid = 512 blocks = 2 blocks/CU =
// 2 waves/EU, so max=2 costs no runtime occupancy.
__global__ __launch_bounds__(256) __attribute__((amdgpu_waves_per_eu(2, 2)))
void grid_vpn_kernel(
    const float* __restrict__ obs,        // (B, 243)
    const float* __restrict__ af,         // (B, 405)
    const float* __restrict__ W1,         // (81, 32)
    const float* __restrict__ W2,         // (32, 32)
    const float* __restrict__ W3,         // (32, 1)
    const float* __restrict__ b3,         // (1,)
    float* __restrict__ out,              // [sym(B) | ir(B) | nr(B) | nsc(B*81)]
    int B)
{
    // Double-buffered staging tile: 2 x (256 rows x 27 cols), flat e = r*27+c.
    __shared__ float buf[2][BROWS * CCH];   // 2 x 27648 B = 55296 B

    const int tid = (int)threadIdx.x;
    const int r0  = (int)blockIdx.x * BROWS;
    const int Bm1 = B - 1;

    // e = t*256 + tid -> (r = e/27, col = e%27); start point for t=0.
    const int sr_r0 = tid / CCH;
    const int sr_c0 = tid - sr_r0 * CCH;

    // ---- precompute af BYTE offsets: the (row,col) walk is identical for all
    // af chunks; per-chunk delta c*108 B folds into the load offset immediate.
    int offs[CCH];
    {
        int r = sr_r0, col = sr_c0;
#pragma unroll
        for (int t = 0; t < CCH; ++t) {
            int rr = r0 + r; rr = (rr <= Bm1) ? rr : Bm1;  // no-op when B%256==0
            offs[t] = (rr * NJ + col) * 4;
            // e += 256  ->  r += 9, col += 13, wrap at 27
            col += 256 - 9 * CCH;
            int w = (col >= CCH) ? 1 : 0;
            r += 9 + w;
            col -= w ? CCH : 0;
        }
    }

    const char* afc = reinterpret_cast<const char*>(af);
    auto loadAF = [&](int c, float (&s)[CCH]) {
#pragma unroll
        for (int t = 0; t < CCH; ++t)
            s[t] = *reinterpret_cast<const float*>(afc + offs[t] + c * CCH * 4);
    };
    auto loadDem = [&](int c, float (&s)[CCH]) {   // only 3 chunks: walk is fine
        const int cb = 2 * STATE + (c - NAF) * CCH;
        int r = sr_r0, col = sr_c0;
#pragma unroll
        for (int t = 0; t < CCH; ++t) {
            int rr = r0 + r; rr = (rr <= Bm1) ? rr : Bm1;
            s[t] = obs[(size_t)rr * OBS_STRIDE + (cb + col)];
            col += 256 - 9 * CCH;
            int w = (col >= CCH) ? 1 : 0;
            r += 9 + w;
            col -= w ? CCH : 0;
        }
    };

    float nsc[STATE];
#pragma unroll
    for (int d = 0; d < STATE; ++d) nsc[d] = 0.0f;
    float ir = 0.0f;

    float stgA[CCH], stgB[CCH];   // depth-2 prefetch, statically indexed (rule #20)

    loadAF(0, stgA);
    loadAF(1, stgB);

    // ---- chunk loop: depth-2 prefetch, LDS dbuf, ONE barrier per chunk ----
    // WAR safety: consume of chunk c (buf[c&1]) and ds_write of chunk c+2
    // (same buffer) are separated by barrier c+1; the lgkm drain before each
    // barrier retires this wave's prior ds_reads as well as its ds_writes.
#pragma unroll
    for (int c = 0; c < NCH; ++c) {
        float (&stg)[CCH] = (c & 1) ? stgB : stgA;   // c is compile-time (full unroll)
        float* lb = &buf[c & 1][0];
        // ds_write chunk c (compiler inserts precise vmcnt waits on reg deps)
#pragma unroll
        for (int t = 0; t < CCH; ++t) lb[t * BROWS + tid] = stg[t];
        // issue chunk c+2 loads NOW -> in flight across the barrier, consumed
        // two chunk-periods later (T14 issue-early; T4 never drain vmcnt here)
        if (c + 2 < NCH) {
            if (c + 2 < NAF) loadAF(c + 2, stg);
            else             loadDem(c + 2, stg);
        }
        asm volatile("s_waitcnt lgkmcnt(0)" ::: "memory");  // my ds writes + prior reads
        __builtin_amdgcn_s_barrier();
        // consume: thread owns row tid; LDS stride 27 (odd) -> conflict-free
        const float* lr = &buf[c & 1][tid * CCH];
        if (c < NAF) {
#pragma unroll
            for (int j = 0; j < CCH; ++j)
                nsc[DST.v[c * CCH + j]] += lr[j];
        } else {
#pragma unroll
            for (int j = 0; j < CCH; ++j)
                ir += fminf(nsc[(c - NAF) * CCH + j], lr[j]);
        }
    }

    // ---- nsc output: flat full-line stores via LDS, 4 rounds of 64 rows ----
    // Alternating buffers -> one lgkm+barrier per round (same WAR argument).
    // Block region out[3B + r0*81 ..] is contiguous, 256-B aligned.
    {
        const int wv = tid >> 6;
        const int ln = tid & 63;
        float* outns = out + 3 * (size_t)B + (size_t)r0 * STATE;
#pragma unroll
        for (int g = 0; g < 4; ++g) {
            float* lb = &buf[g & 1][0];
            if (wv == g) {
#pragma unroll
                for (int j = 0; j < STATE; ++j) lb[ln * STATE + j] = nsc[j];  // stride 81: 2-way, free
            }
            asm volatile("s_waitcnt lgkmcnt(0)" ::: "memory");
            __builtin_amdgcn_s_barrier();
            // 64*81 = 5184 floats = 20*256 + 64; every store full-line aligned
#pragma unroll
            for (int t = 0; t < 20; ++t)
                outns[g * 5184 + t * 256 + tid] = lb[t * 256 + tid];
            if (tid < 64) outns[g * 5184 + 5120 + tid] = lb[5120 + tid];
        }
    }

    // ---- MLP (per-thread, weights via scalar loads) ----
    float x1[H1];
#pragma unroll
    for (int j = 0; j < H1; ++j) x1[j] = 0.0f;
#pragma unroll
    for (int d = 0; d < STATE; ++d) {
        float v = nsc[d];
#pragma unroll
        for (int j = 0; j < H1; ++j) x1[j] = fmaf(v, W1[d * H1 + j], x1[j]);
    }
#pragma unroll
    for (int j = 0; j < H1; ++j) x1[j] = fmaxf(x1[j], 0.0f);

    float x2[H2];
#pragma unroll
    for (int j = 0; j < H2; ++j) x2[j] = 0.0f;
#pragma unroll
    for (int k = 0; k < H1; ++k) {
        float v = x1[k];
#pragma unroll
        for (int j = 0; j < H2; ++j) x2[j] = fmaf(v, W2[k * H2 + j], x2[j]);
    }
#pragma unroll
    for (int j = 0; j < H2; ++j) x2[j] = fmaxf(x2[j], 0.0f);

    float nr = b3[0];
#pragma unroll
    for (int k = 0; k < H2; ++k) nr = fmaf(x2[k], W3[k], nr);

    // ---- scalar outputs (coalesced full lines: b = r0 + tid) ----
    int b = r0 + tid;
    if (b < B) {
        out[b] = ir + nr;            // symbolic_val
        out[(size_t)B + b] = ir;     // immediate_reward
        out[2 * (size_t)B + b] = nr; // next_return
    }
}

extern "C" void kernel_launch(void* const* d_in, const int* in_sizes, int n_in,
                              void* d_out, int out_size, void* d_ws, size_t ws_size,
                              hipStream_t stream) {
    const float* obs = (const float*)d_in[0];
    const float* ac  = (const float*)d_in[1];
    const float* W1  = (const float*)d_in[2];
    const float* W2  = (const float*)d_in[3];
    const float* W3  = (const float*)d_in[4];
    const float* b3  = (const float*)d_in[5];
    float* out = (float*)d_out;

    int B = in_sizes[0] / (3 * STATE);
    int block = BROWS;
    int grid = (B + BROWS - 1) / BROWS;
    hipLaunchKernelGGL(grid_vpn_kernel, dim3(grid), dim3(block), 0, stream,
                       obs, ac, W1, W2, W3, b3, out, B);
}